// Round 4
// baseline (192.430 us; speedup 1.0000x reference)
//
#include <hip/hip_runtime.h>
#include <math.h>

// iSQRT-COV: B=64, C=128, n=3136.
// sigma = G/n - mu mu^T (G = X X^T via split-bf16 MFMA),
// fused Newton-Schulz (5 iters) in LDS; one 256-thread block (4 waves) per
// batch, each wave owns a 64x64 tile (4x4 MFMA frags); Y,Z carried in fp32
// registers across iterations (LDS holds bf16 operand planes only).

#define CC 128
#define NN 3136
#define BB 64
#define KS 7
#define KCHUNK 448            // NN/KS = 14 ksteps of 32
#define MATS (CC * CC)
#define OUTLEN 8256
#define PSTR 136              // ns plane row stride in bf16 (68 dwords)
#define SSTR 34               // gram stage row stride in bf16 (17 dwords, odd)

typedef float f32x4 __attribute__((ext_vector_type(4)));
typedef short s16x8 __attribute__((ext_vector_type(8)));
typedef short s16x4 __attribute__((ext_vector_type(4)));
typedef __bf16 bf16x8 __attribute__((ext_vector_type(8)));

__device__ __forceinline__ unsigned short f2b(float f) {
    unsigned u = __builtin_bit_cast(unsigned, f);
    unsigned r = u + 0x7fffu + ((u >> 16) & 1u);
    return (unsigned short)(r >> 16);
}
__device__ __forceinline__ float b2f(unsigned short s) {
    return __builtin_bit_cast(float, ((unsigned)s) << 16);
}

__device__ __forceinline__ f32x4 MF(s16x8 a, s16x8 b, f32x4 c) {
    return __builtin_amdgcn_mfma_f32_16x16x32_bf16(
        __builtin_bit_cast(bf16x8, a), __builtin_bit_cast(bf16x8, b), c, 0, 0, 0);
}

// ---------------------------------------------------------------------------
// Gram partial via split-bf16 MFMA. grid (BB, KS), block 256 (4 waves).
// ---------------------------------------------------------------------------
__global__ __launch_bounds__(256, 2)
void gram_kernel(const float* __restrict__ x, float* __restrict__ Gpart,
                 float* __restrict__ rspart)
{
    __shared__ short Xs[2][2][128 * SSTR];   // [buf][hi/lo][row*SSTR+k]
    const int b = blockIdx.x, ks = blockIdx.y;
    const int tid  = threadIdx.x;
    const int wave = tid >> 6, lane = tid & 63;
    const int q = lane >> 4, l15 = lane & 15;
    const int i0 = (wave >> 1) * 64, j0 = (wave & 1) * 64;

    const float* __restrict__ Xb = x + (size_t)b * CC * NN + (size_t)ks * KCHUNK;
    const int lrow = tid >> 3;        // 0..31
    const int lf   = tid & 7;         // 0..7

    f32x4 acc[4][4];
#pragma unroll
    for (int rt = 0; rt < 4; ++rt)
#pragma unroll
        for (int ct = 0; ct < 4; ++ct) acc[rt][ct] = (f32x4){0.f, 0.f, 0.f, 0.f};
    float rs[4] = {0.f, 0.f, 0.f, 0.f};

    float4 ld[4];
#pragma unroll
    for (int p = 0; p < 4; ++p)
        ld[p] = *(const float4*)(Xb + (size_t)(lrow + 32 * p) * NN + lf * 4);

#pragma unroll
    for (int p = 0; p < 4; ++p) {
        const float4 v = ld[p];
        rs[p] += v.x + v.y + v.z + v.w;
        float f[4] = {v.x, v.y, v.z, v.w};
        s16x4 h, l;
#pragma unroll
        for (int r = 0; r < 4; ++r) {
            unsigned short hh = f2b(f[r]);
            h[r] = (short)hh;
            l[r] = (short)f2b(f[r] - b2f(hh));
        }
        const int off = (lrow + 32 * p) * SSTR + lf * 4;
        *(s16x4*)(&Xs[0][0][off]) = h;
        *(s16x4*)(&Xs[0][1][off]) = l;
    }
    __syncthreads();

    for (int kt = 0; kt < 14; ++kt) {
        const int cur = kt & 1;
        if (kt < 13) {
#pragma unroll
            for (int p = 0; p < 4; ++p)
                ld[p] = *(const float4*)(Xb + (size_t)(lrow + 32 * p) * NN + (kt + 1) * 32 + lf * 4);
        }
        s16x8 ah[4], al[4], bh[4], bl[4];
#pragma unroll
        for (int t = 0; t < 4; ++t) {
            ah[t] = *(const s16x8*)(&Xs[cur][0][(i0 + t * 16 + l15) * SSTR + q * 8]);
            al[t] = *(const s16x8*)(&Xs[cur][1][(i0 + t * 16 + l15) * SSTR + q * 8]);
            bh[t] = *(const s16x8*)(&Xs[cur][0][(j0 + t * 16 + l15) * SSTR + q * 8]);
            bl[t] = *(const s16x8*)(&Xs[cur][1][(j0 + t * 16 + l15) * SSTR + q * 8]);
        }
#pragma unroll
        for (int rt = 0; rt < 4; ++rt)
#pragma unroll
            for (int ct = 0; ct < 4; ++ct) {
                acc[rt][ct] = MF(ah[rt], bh[ct], acc[rt][ct]);
                acc[rt][ct] = MF(ah[rt], bl[ct], acc[rt][ct]);
                acc[rt][ct] = MF(al[rt], bh[ct], acc[rt][ct]);
            }
        if (kt < 13) {
#pragma unroll
            for (int p = 0; p < 4; ++p) {
                const float4 v = ld[p];
                rs[p] += v.x + v.y + v.z + v.w;
                float f[4] = {v.x, v.y, v.z, v.w};
                s16x4 h, l;
#pragma unroll
                for (int r = 0; r < 4; ++r) {
                    unsigned short hh = f2b(f[r]);
                    h[r] = (short)hh;
                    l[r] = (short)f2b(f[r] - b2f(hh));
                }
                const int off = (lrow + 32 * p) * SSTR + lf * 4;
                *(s16x4*)(&Xs[cur ^ 1][0][off]) = h;
                *(s16x4*)(&Xs[cur ^ 1][1][off]) = l;
            }
            __syncthreads();
        }
    }

    float* __restrict__ Gb = Gpart + (size_t)(ks * BB + b) * MATS;
#pragma unroll
    for (int rt = 0; rt < 4; ++rt)
#pragma unroll
        for (int ct = 0; ct < 4; ++ct)
#pragma unroll
            for (int r = 0; r < 4; ++r) {
                const int m = i0 + rt * 16 + q * 4 + r;
                const int n = j0 + ct * 16 + l15;
                Gb[m * CC + n] = acc[rt][ct][r];
            }
#pragma unroll
    for (int p = 0; p < 4; ++p) {
        float v = rs[p];
        v += __shfl_xor(v, 1);
        v += __shfl_xor(v, 2);
        v += __shfl_xor(v, 4);
        if ((lane & 7) == 0)
            rspart[(size_t)(ks * BB + b) * CC + lrow + 32 * p] = v;
    }
}

// ---------------------------------------------------------------------------
// Fused NS: 256 threads (4 waves), each wave owns a 64x64 tile (4x4 frags).
// Y,Z carried fp32 in regs; LDS planes: Yhi/Ylo (split), Dm/Zm (bf16).
// All NS matrices are symmetric -> transposed packed writes are valid.
// ---------------------------------------------------------------------------
template<bool DUAL>
__device__ __forceinline__ void mm_pass(const short* __restrict__ A1,
                                        const short* __restrict__ A2,
                                        const short* __restrict__ Bp,
                                        int i0, int j0, int l15, int q,
                                        f32x4 acc[4][4])
{
#pragma unroll
    for (int k0 = 0; k0 < 128; k0 += 32) {
        s16x8 a1[4], a2[4], bb[4];
#pragma unroll
        for (int t = 0; t < 4; ++t) {
            a1[t] = *(const s16x8*)(A1 + (i0 + t * 16 + l15) * PSTR + k0 + q * 8);
            if (DUAL)
                a2[t] = *(const s16x8*)(A2 + (i0 + t * 16 + l15) * PSTR + k0 + q * 8);
            bb[t] = *(const s16x8*)(Bp + (j0 + t * 16 + l15) * PSTR + k0 + q * 8);
        }
#pragma unroll
        for (int rt = 0; rt < 4; ++rt)
#pragma unroll
            for (int ct = 0; ct < 4; ++ct) {
                acc[rt][ct] = MF(a1[rt], bb[ct], acc[rt][ct]);
                if (DUAL) acc[rt][ct] = MF(a2[rt], bb[ct], acc[rt][ct]);
            }
    }
}

__global__ __launch_bounds__(256, 1)
void ns_kernel(const float* __restrict__ Gpart, const float* __restrict__ rspart,
               float* __restrict__ out)
{
    __shared__ short Yhi[128 * PSTR];
    __shared__ short Ylo[128 * PSTR];
    __shared__ short Dm [128 * PSTR];
    __shared__ short Zm [128 * PSTR];
    __shared__ float mu[CC];
    __shared__ float red[4];

    const int b = blockIdx.x;
    const int tid  = threadIdx.x;
    const int wave = tid >> 6, lane = tid & 63;
    const int q = lane >> 4, l15 = lane & 15;
    const int i0 = (wave >> 1) * 64, j0 = (wave & 1) * 64;

    // ---- mu ----
    if (tid < CC) {
        float s = 0.f;
#pragma unroll
        for (int ks = 0; ks < KS; ++ks)
            s += rspart[(size_t)(ks * BB + b) * CC + tid];
        mu[tid] = s * (1.0f / NN);
    }
    __syncthreads();

    // ---- sigma (16 float4/thread) + trace ----
    const float4* __restrict__ GP4 = (const float4*)Gpart;
    float4 sig[16];
    float trpart = 0.f;
#pragma unroll
    for (int jj = 0; jj < 16; ++jj) {
        const int idx4 = tid + 256 * jj;
        float4 tb[KS];
#pragma unroll
        for (int ks = 0; ks < KS; ++ks)
            tb[ks] = GP4[(size_t)(ks * BB + b) * 4096 + idx4];
        const int row = idx4 >> 5;
        const int c4  = (idx4 & 31) << 2;
        float g[4] = {0.f, 0.f, 0.f, 0.f};
#pragma unroll
        for (int ks = 0; ks < KS; ++ks) {
            g[0] += tb[ks].x; g[1] += tb[ks].y;
            g[2] += tb[ks].z; g[3] += tb[ks].w;
        }
        float4 sv;
        const float mr = mu[row];
        sv.x = g[0] * (1.0f / NN) - mr * mu[c4 + 0];
        sv.y = g[1] * (1.0f / NN) - mr * mu[c4 + 1];
        sv.z = g[2] * (1.0f / NN) - mr * mu[c4 + 2];
        sv.w = g[3] * (1.0f / NN) - mr * mu[c4 + 3];
        sig[jj] = sv;
        const int dd = row - c4;
        if (dd == 0) trpart += sv.x;
        else if (dd == 1) trpart += sv.y;
        else if (dd == 2) trpart += sv.z;
        else if (dd == 3) trpart += sv.w;
    }
    trpart += __shfl_xor(trpart, 1);
    trpart += __shfl_xor(trpart, 2);
    trpart += __shfl_xor(trpart, 4);
    trpart += __shfl_xor(trpart, 8);
    trpart += __shfl_xor(trpart, 16);
    trpart += __shfl_xor(trpart, 32);
    if (lane == 0) red[wave] = trpart;
    __syncthreads();
    const float tr = red[0] + red[1] + red[2] + red[3];
    const float invtr = 1.0f / tr;
    const float sscale = sqrtf(tr);

    // ---- planes: Y1 = A (split), D1 = 0.5I-0.5A, Z1 = I+D1 ----
#pragma unroll
    for (int jj = 0; jj < 16; ++jj) {
        const int idx4 = tid + 256 * jj;
        const int row = idx4 >> 5;
        const int c4  = (idx4 & 31) << 2;
        const float4 sv = sig[jj];
        float a[4] = {sv.x * invtr, sv.y * invtr, sv.z * invtr, sv.w * invtr};
        s16x4 yh, yl, dv, zv;
#pragma unroll
        for (int r = 0; r < 4; ++r) {
            unsigned short hh = f2b(a[r]);
            yh[r] = (short)hh;
            yl[r] = (short)f2b(a[r] - b2f(hh));
            const float dia = (row == c4 + r) ? 0.5f : 0.0f;
            const float d = dia - 0.5f * a[r];
            dv[r] = (short)f2b(d);
            zv[r] = (short)f2b(((row == c4 + r) ? 1.0f : 0.0f) + d);
        }
        const int off = row * PSTR + c4;
        *(s16x4*)(&Yhi[off]) = yh;
        *(s16x4*)(&Ylo[off]) = yl;
        *(s16x4*)(&Dm[off])  = dv;
        *(s16x4*)(&Zm[off])  = zv;
    }
    __syncthreads();

    // ---- load wave-resident fp32 Y,Z at this wave's frag positions ----
    f32x4 y_reg[4][4], z_reg[4][4];
#pragma unroll
    for (int rt = 0; rt < 4; ++rt)
#pragma unroll
        for (int ct = 0; ct < 4; ++ct) {
            const int m0 = i0 + rt * 16 + q * 4;
            const int n  = j0 + ct * 16 + l15;
            const int off = n * PSTR + m0;
            s16x4 yh = *(s16x4*)(&Yhi[off]);
            s16x4 yl = *(s16x4*)(&Ylo[off]);
            s16x4 zv = *(s16x4*)(&Zm[off]);
#pragma unroll
            for (int r = 0; r < 4; ++r) {
                y_reg[rt][ct][r] = b2f((unsigned short)yh[r]) + b2f((unsigned short)yl[r]);
                z_reg[rt][ct][r] = b2f((unsigned short)zv[r]);
            }
        }

    f32x4 acc[4][4];

    // ---- iter 1: Y2 = Y1 + Y1@D1 (Z1 already = T1) ----
#pragma unroll
    for (int rt = 0; rt < 4; ++rt)
#pragma unroll
        for (int ct = 0; ct < 4; ++ct) acc[rt][ct] = (f32x4){0.f, 0.f, 0.f, 0.f};
    mm_pass<true>(Yhi, Ylo, Dm, i0, j0, l15, q, acc);
    __syncthreads();
#pragma unroll
    for (int rt = 0; rt < 4; ++rt)
#pragma unroll
        for (int ct = 0; ct < 4; ++ct) {
            const int m0 = i0 + rt * 16 + q * 4;
            const int n  = j0 + ct * 16 + l15;
            const int off = n * PSTR + m0;
            s16x4 nh, nl;
#pragma unroll
            for (int r = 0; r < 4; ++r) {
                const float y = y_reg[rt][ct][r] + acc[rt][ct][r];
                y_reg[rt][ct][r] = y;
                unsigned short hh = f2b(y);
                nh[r] = (short)hh;
                nl[r] = (short)f2b(y - b2f(hh));
            }
            *(s16x4*)(&Yhi[off]) = nh;
            *(s16x4*)(&Ylo[off]) = nl;
        }
    __syncthreads();

    // ---- iters 2..5 ----
    for (int it = 2; it <= 5; ++it) {
        // P1: D = 0.5I - 0.5 * Z@Y (Y ~ Yhi: damped path)
#pragma unroll
        for (int rt = 0; rt < 4; ++rt)
#pragma unroll
            for (int ct = 0; ct < 4; ++ct) acc[rt][ct] = (f32x4){0.f, 0.f, 0.f, 0.f};
        mm_pass<false>(Zm, Zm, Yhi, i0, j0, l15, q, acc);
#pragma unroll
        for (int rt = 0; rt < 4; ++rt)
#pragma unroll
            for (int ct = 0; ct < 4; ++ct) {
                const int m0 = i0 + rt * 16 + q * 4;
                const int n  = j0 + ct * 16 + l15;
                s16x4 dv;
#pragma unroll
                for (int r = 0; r < 4; ++r) {
                    const float dia = (m0 + r == n) ? 0.5f : 0.0f;
                    dv[r] = (short)f2b(dia - 0.5f * acc[rt][ct][r]);
                }
                *(s16x4*)(&Dm[n * PSTR + m0]) = dv;
            }
        __syncthreads();

        // P2: Ynew = Y + Y@D (split operands)
#pragma unroll
        for (int rt = 0; rt < 4; ++rt)
#pragma unroll
            for (int ct = 0; ct < 4; ++ct) acc[rt][ct] = (f32x4){0.f, 0.f, 0.f, 0.f};
        mm_pass<true>(Yhi, Ylo, Dm, i0, j0, l15, q, acc);
        __syncthreads();

        if (it < 5) {
            // Y update: regs += acc, re-split to LDS (no LDS reads)
#pragma unroll
            for (int rt = 0; rt < 4; ++rt)
#pragma unroll
                for (int ct = 0; ct < 4; ++ct) {
                    const int m0 = i0 + rt * 16 + q * 4;
                    const int n  = j0 + ct * 16 + l15;
                    const int off = n * PSTR + m0;
                    s16x4 nh, nl;
#pragma unroll
                    for (int r = 0; r < 4; ++r) {
                        const float y = y_reg[rt][ct][r] + acc[rt][ct][r];
                        y_reg[rt][ct][r] = y;
                        unsigned short hh = f2b(y);
                        nh[r] = (short)hh;
                        nl[r] = (short)f2b(y - b2f(hh));
                    }
                    *(s16x4*)(&Yhi[off]) = nh;
                    *(s16x4*)(&Ylo[off]) = nl;
                }
            // no barrier needed: P3 reads only Dm/Zm

            // P3: Znew = Z + D@Z
#pragma unroll
            for (int rt = 0; rt < 4; ++rt)
#pragma unroll
                for (int ct = 0; ct < 4; ++ct) acc[rt][ct] = (f32x4){0.f, 0.f, 0.f, 0.f};
            mm_pass<false>(Dm, Dm, Zm, i0, j0, l15, q, acc);
            __syncthreads();   // all Zm reads done (also covers Y writes)
#pragma unroll
            for (int rt = 0; rt < 4; ++rt)
#pragma unroll
                for (int ct = 0; ct < 4; ++ct) {
                    const int m0 = i0 + rt * 16 + q * 4;
                    const int n  = j0 + ct * 16 + l15;
                    s16x4 zn;
#pragma unroll
                    for (int r = 0; r < 4; ++r) {
                        const float z = z_reg[rt][ct][r] + acc[rt][ct][r];
                        z_reg[rt][ct][r] = z;
                        zn[r] = (short)f2b(z);
                    }
                    *(s16x4*)(&Zm[n * PSTR + m0]) = zn;
                }
            __syncthreads();
        } else {
            // out = triu(Y6) * sqrt(tr), straight from registers
            float* __restrict__ ob = out + (size_t)b * OUTLEN;
#pragma unroll
            for (int rt = 0; rt < 4; ++rt)
#pragma unroll
                for (int ct = 0; ct < 4; ++ct) {
                    const int m0 = i0 + rt * 16 + q * 4;
                    const int n  = j0 + ct * 16 + l15;
#pragma unroll
                    for (int r = 0; r < 4; ++r) {
                        const int m = m0 + r;
                        if (m <= n) {
                            const float y = y_reg[rt][ct][r] + acc[rt][ct][r];
                            ob[m * CC - ((m * (m - 1)) >> 1) + (n - m)] = y * sscale;
                        }
                    }
                }
        }
    }
}

extern "C" void kernel_launch(void* const* d_in, const int* in_sizes, int n_in,
                              void* d_out, int out_size, void* d_ws, size_t ws_size,
                              hipStream_t stream)
{
    (void)in_sizes; (void)n_in; (void)out_size; (void)ws_size;
    const float* x = (const float*)d_in[0];
    float* out = (float*)d_out;
    float* ws  = (float*)d_ws;

    float* rspart = ws;                        // KS*BB*CC floats
    float* Gpart  = ws + (size_t)KS * BB * CC; // KS*BB*MATS floats

    gram_kernel<<<dim3(BB, KS), 256, 0, stream>>>(x, Gpart, rspart);
    ns_kernel<<<dim3(BB), 256, 0, stream>>>(Gpart, rspart, out);
}